// Round 1
// baseline (602.839 us; speedup 1.0000x reference)
//
#include <hip/hip_runtime.h>
#include <stdint.h>

// Problem constants (from reference): x[4,2048,4096] fp32, W[4096,4096] fp32,
// bias[4096] fp32, L[4096,16] fp32, R[16,4096] fp32. out = x @ (W + 2*L@R)^T + b.
#define NTOK     8192      // 4*2048 tokens (M)
#define D_OUT    4096      // N
#define D_IN     4096      // K
#define LORA_DIM 16
#define LORA_SCALE 2.0f    // 32.0 / 16

typedef short  short8  __attribute__((ext_vector_type(8)));   // 8 bf16 = 4 VGPRs (MFMA A/B frag)
typedef float  floatx4 __attribute__((ext_vector_type(4)));   // MFMA C/D frag
typedef unsigned short ushort4v __attribute__((ext_vector_type(4)));

typedef unsigned int u32;
typedef __attribute__((address_space(3))) u32 lds_u32;
typedef __attribute__((address_space(1))) u32 glb_u32;

// fp32 -> bf16 round-to-nearest-even
__device__ __forceinline__ unsigned short f2bf(float f) {
  unsigned int u = __builtin_bit_cast(unsigned int, f);
  u += 0x7FFFu + ((u >> 16) & 1u);
  return (unsigned short)(u >> 16);
}

// async global->LDS, 16B per lane. LDS dest must be wave-uniform base + lane*16.
__device__ __forceinline__ void copy16(const void* g, void* l) {
  __builtin_amdgcn_global_load_lds((glb_u32*)(uintptr_t)g, (lds_u32*)(uintptr_t)l,
                                   16, 0, 0);
}

// ---------------------------------------------------------------------------
// Kernel 1: x (fp32) -> bf16, 4 elems/thread
// ---------------------------------------------------------------------------
__global__ __launch_bounds__(256) void cvt_x(const float* __restrict__ X,
                                             unsigned short* __restrict__ Xb) {
  const size_t i = ((size_t)blockIdx.x * 256 + threadIdx.x) * 4;
  const float4 v = *(const float4*)(X + i);
  ushort4v o;
  o.x = f2bf(v.x); o.y = f2bf(v.y); o.z = f2bf(v.z); o.w = f2bf(v.w);
  *(ushort4v*)(Xb + i) = o;
}

// ---------------------------------------------------------------------------
// Kernel 2: W_eff = W + 2*(L@R), cast to bf16. One block per output row o.
// L[o][:] is block-uniform (scalar loads); R rows are L2-resident (256 KB).
// ---------------------------------------------------------------------------
__global__ __launch_bounds__(256) void make_weff(const float* __restrict__ W,
                                                 const float* __restrict__ L,
                                                 const float* __restrict__ R,
                                                 unsigned short* __restrict__ Wb) {
  const int o = blockIdx.x;
  const int tid = threadIdx.x;
  float l[LORA_DIM];
#pragma unroll
  for (int d = 0; d < LORA_DIM; ++d) l[d] = LORA_SCALE * L[o * LORA_DIM + d];
  for (int i = tid * 4; i < D_IN; i += 256 * 4) {
    const float4 w = *(const float4*)(W + (size_t)o * D_IN + i);
    float a0 = w.x, a1 = w.y, a2 = w.z, a3 = w.w;
#pragma unroll
    for (int d = 0; d < LORA_DIM; ++d) {
      const float4 r = *(const float4*)(R + (size_t)d * D_IN + i);
      a0 += l[d] * r.x; a1 += l[d] * r.y; a2 += l[d] * r.z; a3 += l[d] * r.w;
    }
    ushort4v ov;
    ov.x = f2bf(a0); ov.y = f2bf(a1); ov.z = f2bf(a2); ov.w = f2bf(a3);
    *(ushort4v*)(Wb + (size_t)o * D_IN + i) = ov;
  }
}

// ---------------------------------------------------------------------------
// Kernel 3: C[M,N] = A[M,K](bf16) * B[N,K](bf16)^T + bias, fp32 out.
// m97 structure: 128x128 tile, BK=32, 4 waves in 2x2, each wave 4x4 MFMA
// 16x16x32 tiles; global_load_lds width=16 staging; 2-barrier K-loop.
// ---------------------------------------------------------------------------
#define BM 128
#define BN 128
#define BK 32

__global__ __launch_bounds__(256) void gemm_bt(
    const unsigned short* __restrict__ A,   // [NTOK, D_IN] bf16
    const unsigned short* __restrict__ B,   // [D_OUT, D_IN] bf16 (W_eff)
    const float* __restrict__ bias,
    float* __restrict__ C) {                // [NTOK, D_OUT] fp32
  __shared__ __align__(16) unsigned short sA[BM * BK];  // 8 KB, rows K-contiguous
  __shared__ __align__(16) unsigned short sB[BN * BK];  // 8 KB

  const int tid = threadIdx.x;
  const int m0 = blockIdx.y * BM;
  const int n0 = blockIdx.x * BN;

  // Staging map: thread t -> LDS byte offset t*16 (== row(t>>2)*64B + (t&3)*16B)
  const int sr = tid >> 2;          // row 0..63 (pass 0)
  const int sc = (tid & 3) * 8;     // bf16 col offset 0,8,16,24
  const unsigned short* gA0 = A + (size_t)(m0 + sr) * D_IN + sc;
  const unsigned short* gA1 = gA0 + (size_t)64 * D_IN;
  const unsigned short* gB0 = B + (size_t)(n0 + sr) * D_IN + sc;
  const unsigned short* gB1 = gB0 + (size_t)64 * D_IN;
  unsigned short* lA0 = &sA[sr * BK + sc];
  unsigned short* lA1 = &sA[(sr + 64) * BK + sc];
  unsigned short* lB0 = &sB[sr * BK + sc];
  unsigned short* lB1 = &sB[(sr + 64) * BK + sc];

  // Fragment map (mfma_f32_16x16x32_bf16):
  //  A operand: lane holds A[m=lane&15][k=(lane>>4)*8 + j]
  //  B operand: lane holds B[k=(lane>>4)*8 + j][n=lane&15]  (== Bt[n][k])
  const int lane = tid & 63;
  const int w  = tid >> 6;
  const int wm = (w >> 1) * 64;     // wave's 64x64 subtile origin
  const int wn = (w & 1) * 64;
  const int fr = lane & 15;
  const int fk = (lane >> 4) * 8;

  floatx4 acc[4][4] = {};

  for (int k0 = 0; k0 < D_IN; k0 += BK) {
    copy16(gA0 + k0, lA0);
    copy16(gA1 + k0, lA1);
    copy16(gB0 + k0, lB0);
    copy16(gB1 + k0, lB1);
    __syncthreads();                // drains vmcnt(0) then barrier

    short8 av[4], bv[4];
#pragma unroll
    for (int t = 0; t < 4; ++t) {
      av[t] = *(const short8*)&sA[(wm + t * 16 + fr) * BK + fk];
      bv[t] = *(const short8*)&sB[(wn + t * 16 + fr) * BK + fk];
    }
#pragma unroll
    for (int i = 0; i < 4; ++i)
#pragma unroll
      for (int j = 0; j < 4; ++j)
        acc[i][j] = __builtin_amdgcn_mfma_f32_16x16x32_bf16(av[i], bv[j],
                                                            acc[i][j], 0, 0, 0);
    __syncthreads();                // protect LDS before next stage
  }

  // C/D layout: col = lane&15, row = (lane>>4)*4 + reg (m89/m91-verified)
  const int q = (lane >> 4) * 4;
#pragma unroll
  for (int i = 0; i < 4; ++i) {
    const int row = m0 + wm + i * 16 + q;
#pragma unroll
    for (int j = 0; j < 4; ++j) {
      const int col = n0 + wn + j * 16 + fr;
      const float bs = bias[col];
      const floatx4 v = acc[i][j];
#pragma unroll
      for (int r = 0; r < 4; ++r)
        C[(size_t)(row + r) * D_OUT + col] = v[r] + bs;
    }
  }
}

// ---------------------------------------------------------------------------
extern "C" void kernel_launch(void* const* d_in, const int* in_sizes, int n_in,
                              void* d_out, int out_size, void* d_ws, size_t ws_size,
                              hipStream_t stream) {
  const float* x    = (const float*)d_in[0];
  const float* W    = (const float*)d_in[1];
  const float* bias = (const float*)d_in[2];
  const float* L    = (const float*)d_in[3];
  const float* R    = (const float*)d_in[4];
  float* out = (float*)d_out;

  // Workspace layout: x_bf16 (64 MB) | W_eff bf16 (32 MB)
  const size_t need = ((size_t)NTOK * D_IN + (size_t)D_OUT * D_IN) * sizeof(unsigned short);
  if (ws_size < need) return;  // fail cleanly (all-zero out) rather than corrupt

  unsigned short* xb = (unsigned short*)d_ws;
  unsigned short* wb = xb + (size_t)NTOK * D_IN;

  cvt_x<<<((size_t)NTOK * D_IN) / (256 * 4), 256, 0, stream>>>(x, xb);
  make_weff<<<D_OUT, 256, 0, stream>>>(W, L, R, wb);
  gemm_bt<<<dim3(D_OUT / BN, NTOK / BM), 256, 0, stream>>>(xb, wb, bias, out);
}